// Round 8
// baseline (170.885 us; speedup 1.0000x reference)
//
#include <hip/hip_runtime.h>

#define N_NODES 100000
#define N_EDGES 2000000

typedef __bf16 bf16x8 __attribute__((ext_vector_type(8)));
typedef float f32x4 __attribute__((ext_vector_type(4)));
typedef float f32x16 __attribute__((ext_vector_type(16)));

__device__ __forceinline__ unsigned f2bf_rne(float f) {
  unsigned u = __builtin_bit_cast(unsigned, f);
  u += 0x7FFFu + ((u >> 16) & 1u);
  return u >> 16;
}

// Pack two NON-NEGATIVE f32 into bf16x2, round-half-up.
__device__ __forceinline__ unsigned pack_rhu(float lo, float hi) {
  unsigned ulo = __builtin_bit_cast(unsigned, lo) + 0x8000u;
  unsigned uhi = __builtin_bit_cast(unsigned, hi) + 0x8000u;
  return __builtin_amdgcn_perm(uhi, ulo, 0x07060302u);
}

// |a-b| on a packed bf16 pair -> packed bf16 pair.
__device__ __forceinline__ unsigned absdiff_pack(unsigned a, unsigned b) {
  float alo = __builtin_bit_cast(float, a << 16);
  float ahi = __builtin_bit_cast(float, a & 0xFFFF0000u);
  float blo = __builtin_bit_cast(float, b << 16);
  float bhi = __builtin_bit_cast(float, b & 0xFFFF0000u);
  return pack_rhu(fabsf(alo - blo), fabsf(ahi - bhi));
}

// ---------------------------------------------------------------------------
// Node MLP via MFMA, grid-stride (round-4 version, proven; the residual
// total-minus-edge gap is fixed harness overhead).
// ---------------------------------------------------------------------------
__global__ __launch_bounds__(64, 1) void node_mfma_kernel(
    const float* __restrict__ X, const float* __restrict__ W1,
    const float* __restrict__ b1, const float* __restrict__ W2,
    const float* __restrict__ b2, unsigned short* __restrict__ H) {
  const int lane = threadIdx.x;
  const int l15 = lane & 15;
  const int quad = lane >> 4;

  float w1v[2][4][8], b1v[2][8];
#pragma unroll
  for (int c = 0; c < 2; ++c)
#pragma unroll
    for (int j = 0; j < 8; ++j) {
      int col = c * 32 + quad * 8 + j;
      b1v[c][j] = b1[col];
#pragma unroll
      for (int d = 0; d < 4; ++d) w1v[c][d][j] = W1[d * 64 + col];
    }

  uint4 afr[2][4];
#pragma unroll
  for (int c = 0; c < 2; ++c)
#pragma unroll
    for (int mt = 0; mt < 4; ++mt) {
      unsigned w[4];
#pragma unroll
      for (int p = 0; p < 4; ++p) {
        int k = c * 32 + quad * 8 + 2 * p;
        unsigned lo = f2bf_rne(W2[k * 64 + mt * 16 + l15]);
        unsigned hi = f2bf_rne(W2[(k + 1) * 64 + mt * 16 + l15]);
        w[p] = lo | (hi << 16);
      }
      afr[c][mt] = make_uint4(w[0], w[1], w[2], w[3]);
    }
  float b2v[16];
#pragma unroll
  for (int mt = 0; mt < 4; ++mt)
#pragma unroll
    for (int r = 0; r < 4; ++r) b2v[mt * 4 + r] = b2[mt * 16 + quad * 4 + r];

  const int ntiles = N_NODES / 16;  // 6250
  for (int tile = blockIdx.x; tile < ntiles; tile += gridDim.x) {
    float4 xv = ((const float4*)X)[tile * 16 + l15];

    uint4 bfr[2];
#pragma unroll
    for (int c = 0; c < 2; ++c) {
      unsigned w[4];
#pragma unroll
      for (int p = 0; p < 4; ++p) {
        float h0 = fmaxf(b1v[c][2 * p] + xv.x * w1v[c][0][2 * p] +
                             xv.y * w1v[c][1][2 * p] + xv.z * w1v[c][2][2 * p] +
                             xv.w * w1v[c][3][2 * p],
                         0.f);
        float h1 = fmaxf(b1v[c][2 * p + 1] + xv.x * w1v[c][0][2 * p + 1] +
                             xv.y * w1v[c][1][2 * p + 1] +
                             xv.z * w1v[c][2][2 * p + 1] +
                             xv.w * w1v[c][3][2 * p + 1],
                         0.f);
        w[p] = pack_rhu(h0, h1);
      }
      bfr[c] = make_uint4(w[0], w[1], w[2], w[3]);
    }

    f32x4 acc[4];
#pragma unroll
    for (int mt = 0; mt < 4; ++mt) acc[mt] = (f32x4){0.f, 0.f, 0.f, 0.f};
#pragma unroll
    for (int c = 0; c < 2; ++c)
#pragma unroll
      for (int mt = 0; mt < 4; ++mt)
        acc[mt] = __builtin_amdgcn_mfma_f32_16x16x32_bf16(
            __builtin_bit_cast(bf16x8, afr[c][mt]),
            __builtin_bit_cast(bf16x8, bfr[c]), acc[mt], 0, 0, 0);

    unsigned short* hrow = H + (tile * 16 + l15) * 64;
#pragma unroll
    for (int mt = 0; mt < 4; ++mt) {
      unsigned lo = pack_rhu(fmaxf(acc[mt][0] + b2v[mt * 4 + 0], 0.f),
                             fmaxf(acc[mt][1] + b2v[mt * 4 + 1], 0.f));
      unsigned hi = pack_rhu(fmaxf(acc[mt][2] + b2v[mt * 4 + 2], 0.f),
                             fmaxf(acc[mt][3] + b2v[mt * 4 + 3], 0.f));
      *(uint2*)(hrow + mt * 16 + quad * 4) = make_uint2(lo, hi);
    }
  }
}

// ---------------------------------------------------------------------------
// Edge MLP with 32x32x16 MFMA: one wave = 32 edges/tile (62500 tiles).
// Halves per-edge gather instrs, MFMA instrs, acc traffic, epilogue shfls vs
// the 16x16x32 version (rounds 3/4/7 pinned at 103us across three pipeline
// depths -> bound by per-tile overhead piles, not by uncovered latency).
// Fragment layouts (analogs of the verified 16x16x32 mappings):
//   A[m=l&31][k=(l>>5)*8+j]   B[k=(l>>5)*8+j][n=l&31]
//   D: col=l&31, row=(r&3)+8*(r>>2)+4*(l>>5)   [guide m74/m101]
// We1^T A-frags live in LDS (26 frags x 1KB; 13th k-chunk folds be1 via
// A13[:,0]=be1, B13[0,:]=1 -> no per-lane bias regs). Arch regs ~150 +
// acc 32 AGPR -> fits (256,2) with no spill (WRITE_SIZE ~8MB tripwire).
// ---------------------------------------------------------------------------
__global__ __launch_bounds__(256, 2) void edge_mlp_kernel(
    const unsigned short* __restrict__ H, const int* __restrict__ pairs,
    const float* __restrict__ We1, const float* __restrict__ be1,
    const float* __restrict__ We2, const float* __restrict__ be2,
    float* __restrict__ out) {
  __shared__ uint4 wlds[26 * 64];  // 26 KB
  const int tid = threadIdx.x;

  // Stage A-frags: frag f=c*2+mt, lane ln, elem j:
  //   c<12 : We1[(c*16+(ln>>5)*8+j)*64 + mt*32+(ln&31)]
  //   c==12: j==0 && (ln>>5)==0 ? be1[mt*32+(ln&31)] : 0
  for (int s = tid; s < 26 * 64; s += 256) {
    int f = s >> 6, ln = s & 63;
    int c = f >> 1, mt = f & 1;
    int col = mt * 32 + (ln & 31);
    uint4 val;
    if (c < 12) {
      int kb = c * 16 + (ln >> 5) * 8;
      val.x = f2bf_rne(We1[(kb + 0) * 64 + col]) |
              (f2bf_rne(We1[(kb + 1) * 64 + col]) << 16);
      val.y = f2bf_rne(We1[(kb + 2) * 64 + col]) |
              (f2bf_rne(We1[(kb + 3) * 64 + col]) << 16);
      val.z = f2bf_rne(We1[(kb + 4) * 64 + col]) |
              (f2bf_rne(We1[(kb + 5) * 64 + col]) << 16);
      val.w = f2bf_rne(We1[(kb + 6) * 64 + col]) |
              (f2bf_rne(We1[(kb + 7) * 64 + col]) << 16);
    } else {
      val.x = ((ln >> 5) == 0) ? f2bf_rne(be1[col]) : 0u;
      val.y = 0u;
      val.z = 0u;
      val.w = 0u;
    }
    wlds[s] = val;
  }

  const int lane = tid & 63;
  const int n = lane & 31;   // edge within tile
  const int half = lane >> 5;

  // B-frag for the bias chunk: B13[0][n]=1.0 -> half==0, j==0 elem = 1.0bf16.
  uint4 b13u = make_uint4((half == 0) ? 0x00003F80u : 0u, 0u, 0u, 0u);

  // We2 per-lane constants: row = mt*32 + (r&3)+8*(r>>2)+4*half.
  float we2v[32];
#pragma unroll
  for (int mt = 0; mt < 2; ++mt)
#pragma unroll
    for (int r = 0; r < 16; ++r)
      we2v[mt * 16 + r] = We2[mt * 32 + (r & 3) + 8 * (r >> 2) + 4 * half];
  const float be2v = be2[0];
  __syncthreads();

  const int wid = blockIdx.x * 4 + (tid >> 6);
  const int nw = gridDim.x * 4;
  const int ntiles = N_EDGES / 32;  // 62500
  const int last = ntiles - 1;
  const int2* pairs2 = (const int2*)pairs;
  const uint4* wf = wlds + lane;  // frag f at wf[f*64]

  // Double-buffered gathers: hu chunks 0-3 + hv chunks 0-3 per buffer.
  uint4 g[2][8];
  int2 uvn[2];
#pragma unroll
  for (int k = 0; k < 2; ++k) {
    int t = wid + k * nw;
    t = (t <= last) ? t : last;
    int2 uv = pairs2[t * 32 + n];
    const uint4* pu = (const uint4*)(H + uv.x * 64 + half * 8);
    const uint4* pv = (const uint4*)(H + uv.y * 64 + half * 8);
#pragma unroll
    for (int c = 0; c < 4; ++c) {
      g[k][c] = pu[c * 2];
      g[k][4 + c] = pv[c * 2];
    }
    int tn = wid + (k + 2) * nw;
    tn = (tn <= last) ? tn : last;
    uvn[k] = pairs2[tn * 32 + n];
  }

  for (int base = wid; base < ntiles; base += 2 * nw) {
#pragma unroll
    for (int k = 0; k < 2; ++k) {
      int t = base + k * nw;
      t = (t <= last) ? t : last;  // tail: recompute last tile (same value)

      // |hu-hv| chunks (k 128..191 of E).
      uint4 ab[4];
#pragma unroll
      for (int c = 0; c < 4; ++c) {
        ab[c].x = absdiff_pack(g[k][c].x, g[k][4 + c].x);
        ab[c].y = absdiff_pack(g[k][c].y, g[k][4 + c].y);
        ab[c].z = absdiff_pack(g[k][c].z, g[k][4 + c].z);
        ab[c].w = absdiff_pack(g[k][c].w, g[k][4 + c].w);
      }

      f32x16 acc[2];
      acc[0] = (f32x16)(0.f);
      acc[1] = (f32x16)(0.f);
#pragma unroll
      for (int c = 0; c < 13; ++c) {
        uint4 bu = (c < 8) ? g[k][c] : (c < 12 ? ab[c - 8] : b13u);
        bf16x8 b = __builtin_bit_cast(bf16x8, bu);
#pragma unroll
        for (int mt = 0; mt < 2; ++mt) {
          bf16x8 a = __builtin_bit_cast(bf16x8, wf[(c * 2 + mt) * 64]);
          acc[mt] = __builtin_amdgcn_mfma_f32_32x32x16_bf16(a, b, acc[mt], 0,
                                                            0, 0);
        }
      }

      // Refill buffer k for tile t+2nw (WAR only, no wait).
      {
        const uint4* qu = (const uint4*)(H + uvn[k].x * 64 + half * 8);
        const uint4* qv = (const uint4*)(H + uvn[k].y * 64 + half * 8);
#pragma unroll
        for (int c = 0; c < 4; ++c) {
          g[k][c] = qu[c * 2];
          g[k][4 + c] = qv[c * 2];
        }
        int tn = base + (k + 4) * nw;
        tn = (tn <= last) ? tn : last;
        uvn[k] = pairs2[tn * 32 + n];
      }

      // Epilogue: bias already in acc via chunk 12 -> relu(acc)*We2, sum
      // over this lane's 32 rows, combine the two half-wave partials.
      float s = 0.f;
#pragma unroll
      for (int mt = 0; mt < 2; ++mt)
#pragma unroll
        for (int r = 0; r < 16; ++r)
          s += fmaxf(acc[mt][r], 0.f) * we2v[mt * 16 + r];
      s += __shfl_xor(s, 32);
      if (half == 0) out[t * 32 + n] = s + be2v;
    }
  }
}

extern "C" void kernel_launch(void* const* d_in, const int* in_sizes, int n_in,
                              void* d_out, int out_size, void* d_ws,
                              size_t ws_size, hipStream_t stream) {
  const float* X = (const float*)d_in[0];
  const int* pairs = (const int*)d_in[1];
  const float* W1 = (const float*)d_in[2];
  const float* b1 = (const float*)d_in[3];
  const float* W2 = (const float*)d_in[4];
  const float* b2 = (const float*)d_in[5];
  const float* We1 = (const float*)d_in[6];
  const float* be1 = (const float*)d_in[7];
  const float* We2 = (const float*)d_in[8];
  const float* be2 = (const float*)d_in[9];
  float* out = (float*)d_out;
  unsigned short* H = (unsigned short*)d_ws;  // 100000*64 bf16 = 12.8 MB

  node_mfma_kernel<<<1024, 64, 0, stream>>>(X, W1, b1, W2, b2, H);
  edge_mlp_kernel<<<1024, 256, 0, stream>>>(H, pairs, We1, be1, We2, be2, out);
}